// Round 2
// baseline (42.764 us; speedup 1.0000x reference)
//
#include <hip/hip_runtime.h>
#include <math.h>

#define LOG2E 1.4426950408889634f

// Precompute 0.5*log2(e)*||y_j||^2 for each train point into ws.
__global__ __launch_bounds__(256) void kde_norms(
    const float* __restrict__ trainX, float* __restrict__ norms, int nTrain)
{
    int j = blockIdx.x * 256 + threadIdx.x;
    if (j < nTrain) {
        const float4* p = (const float4*)trainX + j * 4;
        float4 a = p[0], b = p[1], c = p[2], e = p[3];
        float n = a.x*a.x + a.y*a.y + a.z*a.z + a.w*a.w
                + b.x*b.x + b.y*b.y + b.z*b.z + b.w*b.w
                + c.x*c.x + c.y*c.y + c.z*c.z + c.w*c.w
                + e.x*e.x + e.y*e.y + e.z*e.z + e.w*e.w;
        norms[j] = n * (0.5f * LOG2E);
    }
}

// One thread per test point; train components are wave-uniform -> the
// compiler scalarizes trainX/norms loads to s_load, and each dot-product
// FMA is v_fmac_f32 v, s, v (1 SGPR operand: legal). No LDS at all.
// writeFinal==1: write log(sum)-Z to out. Else partial sums to ws.
__global__ __launch_bounds__(256) void kde_main(
    const float* __restrict__ testX, const float* __restrict__ trainX,
    const float* __restrict__ norms, float* __restrict__ wsOrOut,
    int nTest, int nTrain, int trainPer, int writeFinal, float Z)
{
    const int tid = threadIdx.x;
    const int ti  = blockIdx.x * 256 + tid;
    const bool valid = ti < nTest;

    // Test point in VGPRs, pre-scaled by log2(e).
    float x[16];
    float xn2p = 0.0f;
    if (valid) {
        #pragma unroll
        for (int k = 0; k < 4; ++k) {
            float4 v = ((const float4*)testX)[ti * 4 + k];
            x[4*k+0] = v.x * LOG2E;
            x[4*k+1] = v.y * LOG2E;
            x[4*k+2] = v.z * LOG2E;
            x[4*k+3] = v.w * LOG2E;
        }
        float xn = 0.0f;
        #pragma unroll
        for (int d = 0; d < 16; ++d) xn = fmaf(x[d], x[d], xn);
        xn2p = xn * (0.5f / LOG2E);   // = 0.5*log2e*||x||^2
    } else {
        #pragma unroll
        for (int d = 0; d < 16; ++d) x[d] = 0.0f;
    }

    const int trainBegin = blockIdx.y * trainPer;
    const int trainEnd   = min(nTrain, trainBegin + trainPer);

    float a0 = 0.0f, a1 = 0.0f, a2 = 0.0f, a3 = 0.0f;
    int j = trainBegin;
    for (; j + 4 <= trainEnd; j += 4) {
        const float* p0 = trainX + (size_t)(j + 0) * 16;
        const float* p1 = trainX + (size_t)(j + 1) * 16;
        const float* p2 = trainX + (size_t)(j + 2) * 16;
        const float* p3 = trainX + (size_t)(j + 3) * 16;
        float d0 = -(xn2p + norms[j + 0]);
        float d1 = -(xn2p + norms[j + 1]);
        float d2 = -(xn2p + norms[j + 2]);
        float d3 = -(xn2p + norms[j + 3]);
        #pragma unroll
        for (int d = 0; d < 16; ++d) {
            d0 = fmaf(x[d], p0[d], d0);
            d1 = fmaf(x[d], p1[d], d1);
            d2 = fmaf(x[d], p2[d], d2);
            d3 = fmaf(x[d], p3[d], d3);
        }
        a0 += __builtin_amdgcn_exp2f(d0);
        a1 += __builtin_amdgcn_exp2f(d1);
        a2 += __builtin_amdgcn_exp2f(d2);
        a3 += __builtin_amdgcn_exp2f(d3);
    }
    for (; j < trainEnd; ++j) {   // tail (unused for power-of-2 splits)
        const float* p0 = trainX + (size_t)j * 16;
        float d0 = -(xn2p + norms[j]);
        #pragma unroll
        for (int d = 0; d < 16; ++d) d0 = fmaf(x[d], p0[d], d0);
        a0 += __builtin_amdgcn_exp2f(d0);
    }

    float acc = (a0 + a1) + (a2 + a3);
    if (valid) {
        if (writeFinal)
            wsOrOut[ti] = __logf(acc) - Z;
        else
            wsOrOut[blockIdx.y * nTest + ti] = acc;
    }
}

__global__ __launch_bounds__(256) void kde_final(
    const float* __restrict__ ws, float* __restrict__ out,
    int nTest, int S, float Z)
{
    int i = blockIdx.x * 256 + threadIdx.x;
    if (i < nTest) {
        float s = 0.0f;
        for (int k = 0; k < S; ++k) s += ws[k * nTest + i];
        out[i] = __logf(s) - Z;
    }
}

extern "C" void kernel_launch(void* const* d_in, const int* in_sizes, int n_in,
                              void* d_out, int out_size, void* d_ws, size_t ws_size,
                              hipStream_t stream) {
    const float* testX  = (const float*)d_in[0];
    const float* trainX = (const float*)d_in[1];
    float* out = (float*)d_out;

    const int D = 16;
    const int nTest  = in_sizes[0] / D;   // 4096
    const int nTrain = in_sizes[1] / D;   // 8192

    const float Z = 0.5f * (float)D * logf(2.0f * (float)M_PI) + logf((float)nTrain);

    // ws layout: [S * nTest floats: partials][nTrain floats: norms]
    int S = 64;
    while (S > 1 &&
           ((size_t)S * nTest + nTrain) * sizeof(float) > ws_size) S >>= 1;
    float* partials = (float*)d_ws;
    float* normsBuf = (float*)d_ws + (size_t)(S > 1 ? S : 1) * nTest;

    const int gx = (nTest + 255) / 256;

    kde_norms<<<(nTrain + 255) / 256, 256, 0, stream>>>(trainX, normsBuf, nTrain);

    if (S <= 1) {
        dim3 grid(gx, 1);
        kde_main<<<grid, 256, 0, stream>>>(testX, trainX, normsBuf, out,
                                           nTest, nTrain, nTrain, 1, Z);
    } else {
        const int trainPer = (nTrain + S - 1) / S;
        dim3 grid(gx, S);
        kde_main<<<grid, 256, 0, stream>>>(testX, trainX, normsBuf, (float*)d_ws,
                                           nTest, nTrain, trainPer, 0, Z);
        kde_final<<<(nTest + 255) / 256, 256, 0, stream>>>((const float*)d_ws, out,
                                                           nTest, S, Z);
    }
}

// Round 3
// 30.463 us; speedup vs baseline: 1.4038x; 1.4038x over previous
//
#include <hip/hip_runtime.h>
#include <math.h>

#define LOG2E 1.4426950408889634f

typedef short  short8  __attribute__((ext_vector_type(8)));
typedef float  f32x4   __attribute__((ext_vector_type(4)));
typedef unsigned short ushort8 __attribute__((ext_vector_type(8)));

__device__ inline unsigned short f2bf(float f) {   // f32 -> bf16 bits, RNE
    unsigned int u = __float_as_uint(f);
    return (unsigned short)((u + 0x7FFFu + ((u >> 16) & 1u)) >> 16);
}

__device__ inline float row_norm16(const float4 v0, const float4 v1,
                                   const float4 v2, const float4 v3) {
    return v0.x*v0.x + v0.y*v0.y + v0.z*v0.z + v0.w*v0.w
         + v1.x*v1.x + v1.y*v1.y + v1.z*v1.z + v1.w*v1.w
         + v2.x*v2.x + v2.y*v2.y + v2.z*v2.z + v2.w*v2.w
         + v3.x*v3.x + v3.y*v3.y + v3.z*v3.z + v3.w*v3.w;
}

// Pre-pass: train -> bf16 (trainH), 0.5*log2e*||y||^2 (trainN),
//           0.5*log2e*||x||^2 for test (testN).
__global__ __launch_bounds__(256) void kde_prep(
    const float* __restrict__ trainX, const float* __restrict__ testX,
    unsigned short* __restrict__ trainH, float* __restrict__ trainN,
    float* __restrict__ testN, int nTrain, int nTest)
{
    int j = blockIdx.x * 256 + threadIdx.x;
    if (j < nTrain) {
        const float4* p = (const float4*)trainX + (size_t)j * 4;
        float4 v0 = p[0], v1 = p[1], v2 = p[2], v3 = p[3];
        trainN[j] = 0.5f * LOG2E * row_norm16(v0, v1, v2, v3);
        ushort8 h0, h1;
        h0[0]=f2bf(v0.x); h0[1]=f2bf(v0.y); h0[2]=f2bf(v0.z); h0[3]=f2bf(v0.w);
        h0[4]=f2bf(v1.x); h0[5]=f2bf(v1.y); h0[6]=f2bf(v1.z); h0[7]=f2bf(v1.w);
        h1[0]=f2bf(v2.x); h1[1]=f2bf(v2.y); h1[2]=f2bf(v2.z); h1[3]=f2bf(v2.w);
        h1[4]=f2bf(v3.x); h1[5]=f2bf(v3.y); h1[6]=f2bf(v3.z); h1[7]=f2bf(v3.w);
        ((ushort8*)trainH)[(size_t)j*2+0] = h0;
        ((ushort8*)trainH)[(size_t)j*2+1] = h1;
    }
    if (j < nTest) {
        const float4* p = (const float4*)testX + (size_t)j * 4;
        testN[j] = 0.5f * LOG2E * row_norm16(p[0], p[1], p[2], p[3]);
    }
}

// Main: block = 4 waves; wave w owns 16 test rows; blockIdx.y = train chunk.
// Per 16-col tile: one mfma_f32_16x16x32_bf16 with C-init = -(xn2p+yn2p),
// then exp2 + accumulate row-sums in registers.
__global__ __launch_bounds__(256) void kde_mfma(
    const float* __restrict__ testX, const unsigned short* __restrict__ trainH,
    const float* __restrict__ trainN, const float* __restrict__ testN,
    float* __restrict__ partials, int nTest, int nTrain, int chunk)
{
    const int lane = threadIdx.x & 63;
    const int w    = threadIdx.x >> 6;
    const int g    = lane >> 4;       // lane group 0..3
    const int l4   = lane & 15;
    const int m0   = blockIdx.x * 64 + w * 16;

    int m = m0 + l4; if (m >= nTest) m = nTest - 1;   // clamp; store-guarded

    // A fragment: A[m][k], k = g*8+j.  k<16 -> hi(dim k); k>=16 -> lo(dim k-16).
    const float* tp = testX + (size_t)m * 16 + (g & 1) * 8;
    float4 u0 = *(const float4*)tp;
    float4 u1 = *(const float4*)(tp + 4);
    float xv[8] = {u0.x,u0.y,u0.z,u0.w,u1.x,u1.y,u1.z,u1.w};
    short8 afrag;
    #pragma unroll
    for (int i = 0; i < 8; ++i) {
        float f = xv[i] * LOG2E;
        unsigned short hb = f2bf(f);
        float hf = __uint_as_float((unsigned int)hb << 16);
        unsigned short lb = f2bf(f - hf);
        afrag[i] = (short)((g < 2) ? hb : lb);
    }

    // Negated test biases for this lane's 4 C rows: r = m0 + g*4 + reg.
    const int rbase = m0 + g * 4;
    const float nx0 = -testN[min(rbase + 0, nTest - 1)];
    const float nx1 = -testN[min(rbase + 1, nTest - 1)];
    const float nx2 = -testN[min(rbase + 2, nTest - 1)];
    const float nx3 = -testN[min(rbase + 3, nTest - 1)];

    const int nBase  = blockIdx.y * chunk;
    const int nTiles = chunk >> 4;

    float rs0 = 0.0f, rs1 = 0.0f, rs2 = 0.0f, rs3 = 0.0f;
    for (int t = 0; t < nTiles; ++t) {
        const int n  = nBase + t * 16 + l4;
        const bool vn = n < nTrain;
        const int nc = vn ? n : 0;
        short8 b = *(const short8*)(trainH + (size_t)nc * 16 + (g & 1) * 8);
        const float ynv = vn ? trainN[nc] : 1e30f;   // invalid col -> exp2 -> 0
        f32x4 c;
        c[0] = nx0 - ynv; c[1] = nx1 - ynv; c[2] = nx2 - ynv; c[3] = nx3 - ynv;
        c = __builtin_amdgcn_mfma_f32_16x16x32_bf16(afrag, b, c, 0, 0, 0);
        rs0 += __builtin_amdgcn_exp2f(c[0]);
        rs1 += __builtin_amdgcn_exp2f(c[1]);
        rs2 += __builtin_amdgcn_exp2f(c[2]);
        rs3 += __builtin_amdgcn_exp2f(c[3]);
    }

    // Reduce across the 16 columns (low-4 lane bits).
    #pragma unroll
    for (int off = 1; off <= 8; off <<= 1) {
        rs0 += __shfl_xor(rs0, off);
        rs1 += __shfl_xor(rs1, off);
        rs2 += __shfl_xor(rs2, off);
        rs3 += __shfl_xor(rs3, off);
    }
    if (l4 == 0) {
        float* pp = partials + (size_t)blockIdx.y * nTest + rbase;
        if (rbase + 0 < nTest) pp[0] = rs0;
        if (rbase + 1 < nTest) pp[1] = rs1;
        if (rbase + 2 < nTest) pp[2] = rs2;
        if (rbase + 3 < nTest) pp[3] = rs3;
    }
}

__global__ __launch_bounds__(256) void kde_final(
    const float* __restrict__ ws, float* __restrict__ out,
    int nTest, int S, float Z)
{
    int i = blockIdx.x * 256 + threadIdx.x;
    if (i < nTest) {
        float s = 0.0f;
        for (int k = 0; k < S; ++k) s += ws[(size_t)k * nTest + i];
        out[i] = __logf(s) - Z;
    }
}

extern "C" void kernel_launch(void* const* d_in, const int* in_sizes, int n_in,
                              void* d_out, int out_size, void* d_ws, size_t ws_size,
                              hipStream_t stream) {
    const float* testX  = (const float*)d_in[0];
    const float* trainX = (const float*)d_in[1];
    float* out = (float*)d_out;

    const int D = 16;
    const int nTest  = in_sizes[0] / D;   // 4096
    const int nTrain = in_sizes[1] / D;   // 8192

    const float Z = 0.5f * (float)D * logf(2.0f * (float)M_PI) + logf((float)nTrain);

    // Pick split S so ws fits: partials + trainH + trainN + testN.
    int S = 16;
    size_t need;
    for (;;) {
        size_t offH = (((size_t)S * nTest * 4) + 15) & ~(size_t)15;
        need = offH + (size_t)nTrain * 32 + (size_t)nTrain * 4 + (size_t)nTest * 4;
        if (need <= ws_size || S == 1) break;
        S >>= 1;
    }
    float* partials = (float*)d_ws;
    size_t offH = (((size_t)S * nTest * 4) + 15) & ~(size_t)15;
    unsigned short* trainH = (unsigned short*)((char*)d_ws + offH);
    float* trainN = (float*)((char*)d_ws + offH + (size_t)nTrain * 32);
    float* testN  = trainN + nTrain;

    const int chunk = (((nTrain + S - 1) / S) + 15) & ~15;   // multiple of 16

    int prepN = max(nTrain, nTest);
    kde_prep<<<(prepN + 255) / 256, 256, 0, stream>>>(
        trainX, testX, trainH, trainN, testN, nTrain, nTest);

    dim3 grid((nTest + 63) / 64, S);
    kde_mfma<<<grid, 256, 0, stream>>>(
        testX, trainH, trainN, testN, partials, nTest, nTrain, chunk);

    kde_final<<<(nTest + 255) / 256, 256, 0, stream>>>(
        partials, out, nTest, S, Z);
}